// Round 2
// baseline (639.211 us; speedup 1.0000x reference)
//
#include <hip/hip_runtime.h>

#define NND 32768      // total nodes N = B*NNODES
#define NE  262144     // edges
#define HD 128
#define NPAIR 2048     // B*FEAS

__device__ __forceinline__ void fma4(float4& a, float s, const float4& w){
  a.x = fmaf(s, w.x, a.x);
  a.y = fmaf(s, w.y, a.y);
  a.z = fmaf(s, w.z, a.z);
  a.w = fmaf(s, w.w, a.w);
}

// ---------------- output zero-fill ----------------
__global__ __launch_bounds__(256) void k_zero(float4* __restrict__ p, int n4){
  int i = blockIdx.x*256 + threadIdx.x;
  int stride = gridDim.x*256;
  float4 z = make_float4(0.f,0.f,0.f,0.f);
  for (; i < n4; i += stride) p[i] = z;
}

// ---------------- CSR build ----------------
__global__ __launch_bounds__(256) void k_count(const int* __restrict__ dst, int* __restrict__ cnt){
  int e = blockIdx.x*256 + threadIdx.x;
  if (e < NE) atomicAdd(&cnt[dst[e]], 1);
}

__global__ __launch_bounds__(1024) void k_scan(const int* __restrict__ cnt, int* __restrict__ rowp,
                                               float* __restrict__ invdeg){
  __shared__ int part[1024];
  int t = threadIdx.x;
  int base = t*32;
  int local[32];
  int s = 0;
  #pragma unroll
  for (int j=0;j<32;j++){ local[j] = s; s += cnt[base+j]; }
  part[t] = s;
  __syncthreads();
  for (int d=1; d<1024; d<<=1){
    int v = (t>=d) ? part[t-d] : 0;
    __syncthreads();
    part[t] += v;
    __syncthreads();
  }
  int off = (t==0) ? 0 : part[t-1];
  #pragma unroll
  for (int j=0;j<32;j++){
    rowp[base+j] = off + local[j];
    int c = cnt[base+j];
    invdeg[base+j] = 1.0f / (float)(c > 0 ? c : 1);
  }
  if (t == 1023) rowp[NND] = off + s;
}

__global__ __launch_bounds__(256) void k_fill(const int* __restrict__ src, const int* __restrict__ dst,
                                              const int* __restrict__ rowp, int* __restrict__ fillc,
                                              int* __restrict__ csr){
  int e = blockIdx.x*256 + threadIdx.x;
  if (e < NE){
    int d = dst[e];
    int p = atomicAdd(&fillc[d], 1);
    csr[rowp[d] + p] = src[e];
  }
}

// ---------------- layer-0 aggregation (IN=8) ----------------
__global__ __launch_bounds__(256) void k_agg8(const float* __restrict__ x, const int* __restrict__ rowp,
                                              const int* __restrict__ csr, const float* __restrict__ invdeg,
                                              float* __restrict__ z8){
  int i = blockIdx.x*256 + threadIdx.x;
  float s[8] = {0,0,0,0,0,0,0,0};
  int a = rowp[i], bnd = rowp[i+1];
  for (int k=a;k<bnd;k++){
    int j = csr[k];
    const float4* p = (const float4*)&x[(size_t)j*8];
    float4 u0 = p[0], u1 = p[1];
    s[0]+=u0.x; s[1]+=u0.y; s[2]+=u0.z; s[3]+=u0.w;
    s[4]+=u1.x; s[5]+=u1.y; s[6]+=u1.z; s[7]+=u1.w;
  }
  float iv = invdeg[i];
  const float4* xp = (const float4*)&x[(size_t)i*8];
  float4 x0 = xp[0], x1 = xp[1];
  float4 o0, o1;
  o0.x = x0.x + s[0]*iv; o0.y = x0.y + s[1]*iv; o0.z = x0.z + s[2]*iv; o0.w = x0.w + s[3]*iv;
  o1.x = x1.x + s[4]*iv; o1.y = x1.y + s[5]*iv; o1.z = x1.z + s[6]*iv; o1.w = x1.w + s[7]*iv;
  ((float4*)&z8[(size_t)i*8])[0] = o0;
  ((float4*)&z8[(size_t)i*8])[1] = o1;
}

// [N x 8] @ [8 x 128] + bias, ReLU
__global__ __launch_bounds__(256) void k_gemm8(const float* __restrict__ A, const float* __restrict__ W,
                                               const float* __restrict__ bias, float* __restrict__ C){
  __shared__ float Ws[8*HD];
  __shared__ float bs[HD];
  int tid = threadIdx.x;
  for (int u=tid; u<8*HD; u+=256) Ws[u] = W[u];
  if (tid < HD) bs[tid] = bias[tid];
  __syncthreads();
  int g = blockIdx.x*256 + tid;     // over NND*HD
  int row = g >> 7, c = g & 127;
  const float4* a4 = (const float4*)&A[(size_t)row*8];
  float4 a0 = a4[0], a1 = a4[1];
  float s = bs[c];
  s = fmaf(a0.x, Ws[0*128+c], s); s = fmaf(a0.y, Ws[1*128+c], s);
  s = fmaf(a0.z, Ws[2*128+c], s); s = fmaf(a0.w, Ws[3*128+c], s);
  s = fmaf(a1.x, Ws[4*128+c], s); s = fmaf(a1.y, Ws[5*128+c], s);
  s = fmaf(a1.z, Ws[6*128+c], s); s = fmaf(a1.w, Ws[7*128+c], s);
  C[g] = fmaxf(s, 0.0f);
}

// ---------------- main GEMM: [N x 128] @ [128 x 128] + bias (+ReLU) (+BN col stats) ----------------
// 128x128 tile, 256 threads, 8x8 per thread. A staged transposed in LDS (reads along k are b128),
// cols split c0 / c0+64 so Ws b128 reads are 2-way (free). Register-prefetch staging hides HBM latency.
template<int ACT, int STATS>
__global__ __launch_bounds__(256) void k_gemm128(const float* __restrict__ A, const float* __restrict__ W,
                                                 const float* __restrict__ bias, float* __restrict__ C,
                                                 float* __restrict__ part){
  __shared__ float At[32*132];   // [kk][row], stride 132
  __shared__ float Ws[32*128];   // [kk][col]
  const int K = 128;
  int tid = threadIdx.x;
  int r0 = blockIdx.x * 128;
  int tc = tid & 15, tr = tid >> 4;
  int c0 = tc * 4;               // cols c0..c0+3 and c0+64..c0+67
  float4 acc[8][2];
  #pragma unroll
  for (int j=0;j<8;j++){ acc[j][0] = make_float4(0,0,0,0); acc[j][1] = make_float4(0,0,0,0); }

  float4 pa[4], pw[4];
  #pragma unroll
  for (int u=0;u<4;u++){
    int e = tid + u*256;
    pa[u] = *(const float4*)&A[(size_t)(r0 + (e>>3))*K + ((e&7)<<2)];
    pw[u] = *(const float4*)&W[(size_t)(e>>5)*HD + ((e&31)<<2)];
  }
  for (int k0 = 0; k0 < K; k0 += 32){
    __syncthreads();
    #pragma unroll
    for (int u=0;u<4;u++){
      int e = tid + u*256;
      int row = e>>3, kc = (e&7)<<2;
      At[(kc+0)*132 + row] = pa[u].x;
      At[(kc+1)*132 + row] = pa[u].y;
      At[(kc+2)*132 + row] = pa[u].z;
      At[(kc+3)*132 + row] = pa[u].w;
      *(float4*)&Ws[(e>>5)*HD + ((e&31)<<2)] = pw[u];
    }
    __syncthreads();
    if (k0 + 32 < K){
      #pragma unroll
      for (int u=0;u<4;u++){
        int e = tid + u*256;
        pa[u] = *(const float4*)&A[(size_t)(r0 + (e>>3))*K + (k0+32) + ((e&7)<<2)];
        pw[u] = *(const float4*)&W[(size_t)((k0+32) + (e>>5))*HD + ((e&31)<<2)];
      }
    }
    #pragma unroll
    for (int kk=0; kk<32; kk++){
      float4 a0 = *(const float4*)&At[kk*132 + tr*8];
      float4 a1 = *(const float4*)&At[kk*132 + tr*8 + 4];
      float4 w0 = *(const float4*)&Ws[kk*HD + c0];
      float4 w1 = *(const float4*)&Ws[kk*HD + c0 + 64];
      fma4(acc[0][0], a0.x, w0); fma4(acc[0][1], a0.x, w1);
      fma4(acc[1][0], a0.y, w0); fma4(acc[1][1], a0.y, w1);
      fma4(acc[2][0], a0.z, w0); fma4(acc[2][1], a0.z, w1);
      fma4(acc[3][0], a0.w, w0); fma4(acc[3][1], a0.w, w1);
      fma4(acc[4][0], a1.x, w0); fma4(acc[4][1], a1.x, w1);
      fma4(acc[5][0], a1.y, w0); fma4(acc[5][1], a1.y, w1);
      fma4(acc[6][0], a1.z, w0); fma4(acc[6][1], a1.z, w1);
      fma4(acc[7][0], a1.w, w0); fma4(acc[7][1], a1.w, w1);
    }
  }
  float4 b0 = *(const float4*)&bias[c0];
  float4 b1 = *(const float4*)&bias[c0+64];
  float4 s0 = make_float4(0,0,0,0), s1 = s0, q0 = s0, q1 = s0;
  if (STATS) __syncthreads();     // all LDS reads done before reuse as stats scratch
  #pragma unroll
  for (int j=0;j<8;j++){
    int row = r0 + tr*8 + j;
    float4 v0 = acc[j][0], v1 = acc[j][1];
    v0.x += b0.x; v0.y += b0.y; v0.z += b0.z; v0.w += b0.w;
    v1.x += b1.x; v1.y += b1.y; v1.z += b1.z; v1.w += b1.w;
    if (ACT == 1){
      v0.x = fmaxf(v0.x,0.f); v0.y = fmaxf(v0.y,0.f); v0.z = fmaxf(v0.z,0.f); v0.w = fmaxf(v0.w,0.f);
      v1.x = fmaxf(v1.x,0.f); v1.y = fmaxf(v1.y,0.f); v1.z = fmaxf(v1.z,0.f); v1.w = fmaxf(v1.w,0.f);
    }
    *(float4*)&C[(size_t)row*HD + c0] = v0;
    *(float4*)&C[(size_t)row*HD + c0 + 64] = v1;
    if (STATS){
      s0.x += v0.x; s0.y += v0.y; s0.z += v0.z; s0.w += v0.w;
      s1.x += v1.x; s1.y += v1.y; s1.z += v1.z; s1.w += v1.w;
      q0.x = fmaf(v0.x,v0.x,q0.x); q0.y = fmaf(v0.y,v0.y,q0.y);
      q0.z = fmaf(v0.z,v0.z,q0.z); q0.w = fmaf(v0.w,v0.w,q0.w);
      q1.x = fmaf(v1.x,v1.x,q1.x); q1.y = fmaf(v1.y,v1.y,q1.y);
      q1.z = fmaf(v1.z,v1.z,q1.z); q1.w = fmaf(v1.w,v1.w,q1.w);
    }
  }
  if (STATS){
    *(float4*)&At[tr*HD + c0]      = s0;
    *(float4*)&At[tr*HD + c0 + 64] = s1;
    *(float4*)&Ws[tr*HD + c0]      = q0;
    *(float4*)&Ws[tr*HD + c0 + 64] = q1;
    __syncthreads();
    if (tid < HD){
      float s = 0.f, q = 0.f;
      #pragma unroll
      for (int t=0;t<16;t++){ s += At[t*HD + tid]; q += Ws[t*HD + tid]; }
      part[blockIdx.x*HD + tid] = s;
      part[256*HD + blockIdx.x*HD + tid] = q;
    }
  }
}

// ---------------- BN finalize (sums 256 block partials; deterministic, no atomics) ----------------
__global__ __launch_bounds__(128) void k_bn_fin(const float* __restrict__ part, const float* __restrict__ gamma,
                                                const float* __restrict__ beta, float* __restrict__ scale,
                                                float* __restrict__ shift){
  int f = threadIdx.x;
  float s = 0.f, q = 0.f;
  for (int b=0;b<256;b++){ s += part[b*HD+f]; q += part[256*HD + b*HD + f]; }
  float mu  = s * (1.0f/NND);
  float var = q * (1.0f/NND) - mu*mu;
  float sc  = gamma[f] * rsqrtf(var + 1e-5f);
  scale[f] = sc;
  shift[f] = beta[f] - mu*sc;
}

// ---------------- fused: BN-apply (folded) + mean-aggregate + npool/gsum accumulate ----------------
// z = sc*(raw_i + invdeg*sum_j raw_j) + sh*(1 + has_neighbors);  v_i = sc*raw_i+sh feeds npool/gsum.
__global__ __launch_bounds__(128) void k_agg_bn(const float* __restrict__ raw, const int* __restrict__ rowp,
                                                const int* __restrict__ csr, const float* __restrict__ invdeg,
                                                const float* __restrict__ scale, const float* __restrict__ shift,
                                                float* __restrict__ z, float* __restrict__ npool,
                                                float* __restrict__ gsum, int first){
  int f = threadIdx.x;
  int n0 = blockIdx.x * 16;       // 16 nodes/block, always same batch (16 | 1024)
  float sc = scale[f], sh = shift[f];
  float g = 0.f;
  for (int r = 0; r < 16; r++){
    int i = n0 + r;
    int a = rowp[i], bnd = rowp[i+1];
    float s = 0.f;
    for (int k = a; k < bnd; k++) s += raw[(size_t)csr[k]*HD + f];
    size_t idx = (size_t)i*HD + f;
    float vi = fmaf(raw[idx], sc, sh);
    float zz = vi + fmaf(invdeg[i]*sc, s, (bnd > a) ? sh : 0.f);
    z[idx] = zz;
    float np = first ? vi : (npool[idx] + vi);
    npool[idx] = np;
    g += vi;
  }
  atomicAdd(&gsum[(n0 >> 10)*HD + f], g);
}

// final layer: BN-apply + npool/gsum only (no aggregation needed after layer 3)
__global__ __launch_bounds__(128) void k_bn_acc(const float* __restrict__ raw, const float* __restrict__ scale,
                                                const float* __restrict__ shift, float* __restrict__ npool,
                                                float* __restrict__ gsum){
  int f = threadIdx.x;
  int r0 = blockIdx.x*32;
  int b = r0 >> 10;
  float sc = scale[f], sh = shift[f];
  float g = 0.f;
  for (int r=0;r<32;r++){
    size_t idx = (size_t)(r0+r)*HD + f;
    float v = fmaf(raw[idx], sc, sh);
    npool[idx] += v;
    g += v;
  }
  atomicAdd(&gsum[b*HD+f], g);
}

// ---------------- policy path (selected 4096 node instances) ----------------
__global__ __launch_bounds__(256) void k_build_aug(const int* __restrict__ mrows, const int* __restrict__ mcols,
                                                   const float* __restrict__ npool, const float* __restrict__ gsum,
                                                   float* __restrict__ aug){
  int idx = blockIdx.x;     // 0..4095: first 2048 = row nodes, next 2048 = col nodes
  int t = threadIdx.x;
  int j = idx & 2047;
  int rg = mrows[j];
  int b = rg >> 10;
  int g = (idx >= 2048) ? ((b << 10) | mcols[j]) : rg;
  float v;
  if (t < 128) v = npool[(size_t)g*HD + t];
  else         v = gsum[b*HD + (t-128)] * (1.0f/1024.0f);
  aug[(size_t)idx*256 + t] = v;
}

// fused policy layer: C = tanh(A@W1+b1)@W2+b2.  64-row tile, T kept in LDS.
template<int K1>
__global__ __launch_bounds__(256) void k_pol(const float* __restrict__ A, const float* __restrict__ W1,
                                             const float* __restrict__ b1, const float* __restrict__ W2,
                                             const float* __restrict__ b2, float* __restrict__ C){
  __shared__ float S1[32*128 + 64*36];   // phase1: W chunk @0, A chunk @4096; phase2: W2 chunk @0
  __shared__ float T[64*132];
  int tid = threadIdx.x;
  int r0 = blockIdx.x * 64;
  int tc = tid & 15, rg = tid >> 4;
  int c0 = tc * 4;
  float4 acc0[4], acc1[4];
  #pragma unroll
  for (int j=0;j<4;j++){ acc0[j] = make_float4(0,0,0,0); acc1[j] = make_float4(0,0,0,0); }
  for (int k0 = 0; k0 < K1; k0 += 32){
    __syncthreads();
    #pragma unroll
    for (int u=0;u<4;u++){
      int e = tid + u*256;
      *(float4*)&S1[(e>>5)*HD + ((e&31)<<2)] = *(const float4*)&W1[(size_t)(k0 + (e>>5))*HD + ((e&31)<<2)];
    }
    #pragma unroll
    for (int u=0;u<2;u++){
      int e = tid + u*256;
      *(float4*)&S1[4096 + (e>>3)*36 + ((e&7)<<2)] = *(const float4*)&A[(size_t)(r0 + (e>>3))*K1 + k0 + ((e&7)<<2)];
    }
    __syncthreads();
    #pragma unroll
    for (int kk=0; kk<32; kk+=4){
      float4 w0[4], w1[4];
      #pragma unroll
      for (int q=0;q<4;q++){
        w0[q] = *(const float4*)&S1[(kk+q)*HD + c0];
        w1[q] = *(const float4*)&S1[(kk+q)*HD + c0 + 64];
      }
      #pragma unroll
      for (int j=0;j<4;j++){
        float4 av = *(const float4*)&S1[4096 + (rg+16*j)*36 + kk];
        fma4(acc0[j], av.x, w0[0]); fma4(acc1[j], av.x, w1[0]);
        fma4(acc0[j], av.y, w0[1]); fma4(acc1[j], av.y, w1[1]);
        fma4(acc0[j], av.z, w0[2]); fma4(acc1[j], av.z, w1[2]);
        fma4(acc0[j], av.w, w0[3]); fma4(acc1[j], av.w, w1[3]);
      }
    }
  }
  {
    float4 bA = *(const float4*)&b1[c0];
    float4 bB = *(const float4*)&b1[c0+64];
    #pragma unroll
    for (int j=0;j<4;j++){
      int r = rg + 16*j;
      float4 v0 = acc0[j], v1 = acc1[j];
      v0.x = tanhf(v0.x + bA.x); v0.y = tanhf(v0.y + bA.y);
      v0.z = tanhf(v0.z + bA.z); v0.w = tanhf(v0.w + bA.w);
      v1.x = tanhf(v1.x + bB.x); v1.y = tanhf(v1.y + bB.y);
      v1.z = tanhf(v1.z + bB.z); v1.w = tanhf(v1.w + bB.w);
      *(float4*)&T[r*132 + c0] = v0;
      *(float4*)&T[r*132 + c0 + 64] = v1;
    }
  }
  float4 d0[4], d1[4];
  #pragma unroll
  for (int j=0;j<4;j++){ d0[j] = make_float4(0,0,0,0); d1[j] = make_float4(0,0,0,0); }
  for (int k0 = 0; k0 < HD; k0 += 32){
    __syncthreads();   // T visible (first iter); previous S1 reads done
    #pragma unroll
    for (int u=0;u<4;u++){
      int e = tid + u*256;
      *(float4*)&S1[(e>>5)*HD + ((e&31)<<2)] = *(const float4*)&W2[(size_t)(k0 + (e>>5))*HD + ((e&31)<<2)];
    }
    __syncthreads();
    #pragma unroll
    for (int kk=0; kk<32; kk+=4){
      float4 w0[4], w1[4];
      #pragma unroll
      for (int q=0;q<4;q++){
        w0[q] = *(const float4*)&S1[(kk+q)*HD + c0];
        w1[q] = *(const float4*)&S1[(kk+q)*HD + c0 + 64];
      }
      #pragma unroll
      for (int j=0;j<4;j++){
        float4 av = *(const float4*)&T[(rg+16*j)*132 + k0 + kk];
        fma4(d0[j], av.x, w0[0]); fma4(d1[j], av.x, w1[0]);
        fma4(d0[j], av.y, w0[1]); fma4(d1[j], av.y, w1[1]);
        fma4(d0[j], av.z, w0[2]); fma4(d1[j], av.z, w1[2]);
        fma4(d0[j], av.w, w0[3]); fma4(d1[j], av.w, w1[3]);
      }
    }
  }
  float4 bA = *(const float4*)&b2[c0];
  float4 bB = *(const float4*)&b2[c0+64];
  #pragma unroll
  for (int j=0;j<4;j++){
    int row = r0 + rg + 16*j;
    float4 v0 = d0[j], v1 = d1[j];
    v0.x += bA.x; v0.y += bA.y; v0.z += bA.z; v0.w += bA.w;
    v1.x += bB.x; v1.y += bB.y; v1.z += bB.z; v1.w += bB.w;
    *(float4*)&C[(size_t)row*HD + c0] = v0;
    *(float4*)&C[(size_t)row*HD + c0 + 64] = v1;
  }
}

// score + per-batch sparse softmax (dedup of repeated cells) + scatter
__global__ __launch_bounds__(64) void k_score(const float* __restrict__ Z, const int* __restrict__ mrows,
                                              const int* __restrict__ mcols, float* __restrict__ out){
  __shared__ int rr[64]; __shared__ int cc[64]; __shared__ float red[64];
  int b = blockIdx.x, f = threadIdx.x;
  int i = b*64 + f;
  int rg = mrows[i];
  int row = rg & 1023;
  int col = mcols[i];
  const float4* zr = (const float4*)&Z[(size_t)i*HD];
  const float4* zc = (const float4*)&Z[(size_t)(NPAIR + i)*HD];
  float s = 0.f;
  #pragma unroll
  for (int k=0;k<32;k++){
    float4 a = zr[k], c = zc[k];
    s = fmaf(a.x,c.x, fmaf(a.y,c.y, fmaf(a.z,c.z, fmaf(a.w,c.w, s))));
  }
  rr[f]=row; cc[f]=col; red[f]=s;
  __syncthreads();
  for (int d=32; d>0; d>>=1){
    if (f<d) red[f] = fmaxf(red[f], red[f+d]);
    __syncthreads();
  }
  float m = red[0];
  __syncthreads();
  bool first = true;
  for (int j=0;j<f;j++) if (rr[j]==row && cc[j]==col) first = false;
  float e = expf(s - m);
  red[f] = first ? e : 0.0f;
  __syncthreads();
  for (int d=32; d>0; d>>=1){
    if (f<d) red[f] += red[f+d];
    __syncthreads();
  }
  float denom = red[0];
  out[(size_t)b*1048576 + row*1024 + col] = e / denom;
}

extern "C" void kernel_launch(void* const* d_in, const int* in_sizes, int n_in,
                              void* d_out, int out_size, void* d_ws, size_t ws_size,
                              hipStream_t stream){
  const float* x     = (const float*)d_in[0];
  const int*   ei    = (const int*)d_in[1];
  const int*   mrows = (const int*)d_in[3];
  const int*   mcols = (const int*)d_in[4];
  const float* g0w1  = (const float*)d_in[5];
  const float* g0b1  = (const float*)d_in[6];
  const float* g0w2  = (const float*)d_in[7];
  const float* g0b2  = (const float*)d_in[8];
  const float* gw1   = (const float*)d_in[9];
  const float* gb1   = (const float*)d_in[10];
  const float* gw2   = (const float*)d_in[11];
  const float* gb2   = (const float*)d_in[12];
  const float* bng   = (const float*)d_in[13];
  const float* bnb   = (const float*)d_in[14];
  const float* p0w1  = (const float*)d_in[15];
  const float* p0b1  = (const float*)d_in[16];
  const float* p0w2  = (const float*)d_in[17];
  const float* p0b2  = (const float*)d_in[18];
  const float* pw1   = (const float*)d_in[19];
  const float* pb1   = (const float*)d_in[20];
  const float* pw2   = (const float*)d_in[21];
  const float* pb2   = (const float*)d_in[22];

  float* fw    = (float*)d_ws;
  float* bufRaw= fw;                        // N*H
  float* bufZ  = fw + 4194304;              // N*H
  float* bufA  = fw + 8388608;              // N*H
  float* npool = fw + 12582912;             // N*H
  float* z8    = fw + 16777216;             // N*8
  float* invdeg= fw + 17039360;             // N
  float* bnsc  = fw + 17072128;             // H
  float* bnsh  = fw + 17072256;             // H
  float* part  = fw + 17072384;             // 2*256*H
  int*   cnt   = (int*)(fw + 17137920);     // N
  int*   fillc = cnt + NND;                 // N
  float* gsum  = (float*)(fillc + NND);     // B*H
  int*   rowp  = (int*)(gsum + 4096);       // N+1
  int*   csr   = rowp + NND + 1;            // E
  float* aug   = bufA;                      // 4096*256 (after GIN)
  float* pX    = bufZ;                      // 4096*128
  float* pY    = bufZ + 524288;             // 4096*128
  float* pZ    = bufRaw;                    // 4096*128

  const int* src = ei;
  const int* dst = ei + NE;

  hipLaunchKernelGGL(k_zero, dim3(2048), dim3(256), 0, stream, (float4*)d_out, out_size/4);
  hipMemsetAsync(cnt, 0, (size_t)(NND + NND + 4096)*4, stream);   // cnt, fillc, gsum

  hipLaunchKernelGGL(k_count, dim3(NE/256), dim3(256), 0, stream, dst, cnt);
  hipLaunchKernelGGL(k_scan, dim3(1), dim3(1024), 0, stream, cnt, rowp, invdeg);
  hipLaunchKernelGGL(k_fill, dim3(NE/256), dim3(256), 0, stream, src, dst, rowp, fillc, csr);

  // layer 0
  hipLaunchKernelGGL(k_agg8, dim3(NND/256), dim3(256), 0, stream, x, rowp, csr, invdeg, z8);
  hipLaunchKernelGGL(k_gemm8, dim3(NND*HD/256), dim3(256), 0, stream, z8, g0w1, g0b1, bufA);
  hipLaunchKernelGGL((k_gemm128<1,1>), dim3(NND/128), dim3(256), 0, stream, bufA, g0w2, g0b2, bufRaw, part);
  hipLaunchKernelGGL(k_bn_fin, dim3(1), dim3(128), 0, stream, part, bng, bnb, bnsc, bnsh);

  // layers 1..3 (agg of layer l consumes raw of layer l-1 and accumulates its npool/gsum)
  for (int l=0;l<3;l++){
    hipLaunchKernelGGL(k_agg_bn, dim3(NND/16), dim3(128), 0, stream, bufRaw, rowp, csr, invdeg,
                       bnsc, bnsh, bufZ, npool, gsum, (l==0) ? 1 : 0);
    hipLaunchKernelGGL((k_gemm128<1,0>), dim3(NND/128), dim3(256), 0, stream, bufZ, gw1 + l*16384, gb1 + l*128, bufA, part);
    hipLaunchKernelGGL((k_gemm128<1,1>), dim3(NND/128), dim3(256), 0, stream, bufA, gw2 + l*16384, gb2 + l*128, bufRaw, part);
    hipLaunchKernelGGL(k_bn_fin, dim3(1), dim3(128), 0, stream, part, bng + (l+1)*128, bnb + (l+1)*128, bnsc, bnsh);
  }
  // layer 3's npool/gsum contribution
  hipLaunchKernelGGL(k_bn_acc, dim3(NND/32), dim3(128), 0, stream, bufRaw, bnsc, bnsh, npool, gsum);

  // policy on the 4096 referenced node instances only
  hipLaunchKernelGGL(k_build_aug, dim3(4096), dim3(256), 0, stream, mrows, mcols, npool, gsum, aug);
  hipLaunchKernelGGL((k_pol<256>), dim3(64), dim3(256), 0, stream, aug, p0w1, p0b1, p0w2, p0b2, pX);
  hipLaunchKernelGGL((k_pol<128>), dim3(64), dim3(256), 0, stream, pX, pw1, pb1, pw2, pb2, pY);
  hipLaunchKernelGGL((k_pol<128>), dim3(64), dim3(256), 0, stream, pY, pw1 + 16384, pb1 + 128, pw2 + 16384, pb2 + 128, pZ);

  hipLaunchKernelGGL(k_score, dim3(32), dim3(64), 0, stream, pZ, mrows, mcols, (float*)d_out);
}

// Round 3
// 573.461 us; speedup vs baseline: 1.1147x; 1.1147x over previous
//
#include <hip/hip_runtime.h>

#define NND 32768      // total nodes N = B*NNODES
#define NE  262144     // edges
#define HD 128
#define NPAIR 2048     // B*FEAS

__device__ __forceinline__ void fma4(float4& a, float s, const float4& w){
  a.x = fmaf(s, w.x, a.x);
  a.y = fmaf(s, w.y, a.y);
  a.z = fmaf(s, w.z, a.z);
  a.w = fmaf(s, w.w, a.w);
}

// ---------------- output zero-fill ----------------
__global__ __launch_bounds__(256) void k_zero(float4* __restrict__ p, int n4){
  int i = blockIdx.x*256 + threadIdx.x;
  int stride = gridDim.x*256;
  float4 z = make_float4(0.f,0.f,0.f,0.f);
  for (; i < n4; i += stride) p[i] = z;
}

// ---------------- CSR build ----------------
__global__ __launch_bounds__(256) void k_count(const int* __restrict__ dst, int* __restrict__ cnt){
  int e = blockIdx.x*256 + threadIdx.x;
  if (e < NE) atomicAdd(&cnt[dst[e]], 1);
}

__global__ __launch_bounds__(1024) void k_scan(const int* __restrict__ cnt, int* __restrict__ rowp,
                                               float* __restrict__ invdeg){
  __shared__ int part[1024];
  int t = threadIdx.x;
  int base = t*32;
  int local[32];
  int s = 0;
  #pragma unroll
  for (int j=0;j<32;j++){ local[j] = s; s += cnt[base+j]; }
  part[t] = s;
  __syncthreads();
  for (int d=1; d<1024; d<<=1){
    int v = (t>=d) ? part[t-d] : 0;
    __syncthreads();
    part[t] += v;
    __syncthreads();
  }
  int off = (t==0) ? 0 : part[t-1];
  #pragma unroll
  for (int j=0;j<32;j++){
    rowp[base+j] = off + local[j];
    int c = cnt[base+j];
    invdeg[base+j] = 1.0f / (float)(c > 0 ? c : 1);
  }
  if (t == 1023) rowp[NND] = off + s;
}

__global__ __launch_bounds__(256) void k_fill(const int* __restrict__ src, const int* __restrict__ dst,
                                              const int* __restrict__ rowp, int* __restrict__ fillc,
                                              int* __restrict__ csr){
  int e = blockIdx.x*256 + threadIdx.x;
  if (e < NE){
    int d = dst[e];
    int p = atomicAdd(&fillc[d], 1);
    csr[rowp[d] + p] = src[e];
  }
}

// ---------------- layer-0 aggregation (IN=8) ----------------
__global__ __launch_bounds__(256) void k_agg8(const float* __restrict__ x, const int* __restrict__ rowp,
                                              const int* __restrict__ csr, const float* __restrict__ invdeg,
                                              float* __restrict__ z8){
  int i = blockIdx.x*256 + threadIdx.x;
  float s[8] = {0,0,0,0,0,0,0,0};
  int a = rowp[i], bnd = rowp[i+1];
  for (int k=a;k<bnd;k++){
    int j = csr[k];
    const float4* p = (const float4*)&x[(size_t)j*8];
    float4 u0 = p[0], u1 = p[1];
    s[0]+=u0.x; s[1]+=u0.y; s[2]+=u0.z; s[3]+=u0.w;
    s[4]+=u1.x; s[5]+=u1.y; s[6]+=u1.z; s[7]+=u1.w;
  }
  float iv = invdeg[i];
  const float4* xp = (const float4*)&x[(size_t)i*8];
  float4 x0 = xp[0], x1 = xp[1];
  float4 o0, o1;
  o0.x = x0.x + s[0]*iv; o0.y = x0.y + s[1]*iv; o0.z = x0.z + s[2]*iv; o0.w = x0.w + s[3]*iv;
  o1.x = x1.x + s[4]*iv; o1.y = x1.y + s[5]*iv; o1.z = x1.z + s[6]*iv; o1.w = x1.w + s[7]*iv;
  ((float4*)&z8[(size_t)i*8])[0] = o0;
  ((float4*)&z8[(size_t)i*8])[1] = o1;
}

// [N x 8] @ [8 x 128] + bias, ReLU
__global__ __launch_bounds__(256) void k_gemm8(const float* __restrict__ A, const float* __restrict__ W,
                                               const float* __restrict__ bias, float* __restrict__ C){
  __shared__ float Ws[8*HD];
  __shared__ float bs[HD];
  int tid = threadIdx.x;
  for (int u=tid; u<8*HD; u+=256) Ws[u] = W[u];
  if (tid < HD) bs[tid] = bias[tid];
  __syncthreads();
  int g = blockIdx.x*256 + tid;     // over NND*HD
  int row = g >> 7, c = g & 127;
  const float4* a4 = (const float4*)&A[(size_t)row*8];
  float4 a0 = a4[0], a1 = a4[1];
  float s = bs[c];
  s = fmaf(a0.x, Ws[0*128+c], s); s = fmaf(a0.y, Ws[1*128+c], s);
  s = fmaf(a0.z, Ws[2*128+c], s); s = fmaf(a0.w, Ws[3*128+c], s);
  s = fmaf(a1.x, Ws[4*128+c], s); s = fmaf(a1.y, Ws[5*128+c], s);
  s = fmaf(a1.z, Ws[6*128+c], s); s = fmaf(a1.w, Ws[7*128+c], s);
  C[g] = fmaxf(s, 0.0f);
}

// ---------------- main GEMM: [N x 128] @ [128 x 128] + bias (+ReLU) (+BN col stats) ----------------
template<int ACT, int STATS>
__global__ __launch_bounds__(256) void k_gemm128(const float* __restrict__ A, const float* __restrict__ W,
                                                 const float* __restrict__ bias, float* __restrict__ C,
                                                 float* __restrict__ part){
  __shared__ float At[32*132];   // [kk][row], stride 132
  __shared__ float Ws[32*128];   // [kk][col]
  const int K = 128;
  int tid = threadIdx.x;
  int r0 = blockIdx.x * 128;
  int tc = tid & 15, tr = tid >> 4;
  int c0 = tc * 4;               // cols c0..c0+3 and c0+64..c0+67
  float4 acc[8][2];
  #pragma unroll
  for (int j=0;j<8;j++){ acc[j][0] = make_float4(0,0,0,0); acc[j][1] = make_float4(0,0,0,0); }

  float4 pa[4], pw[4];
  #pragma unroll
  for (int u=0;u<4;u++){
    int e = tid + u*256;
    pa[u] = *(const float4*)&A[(size_t)(r0 + (e>>3))*K + ((e&7)<<2)];
    pw[u] = *(const float4*)&W[(size_t)(e>>5)*HD + ((e&31)<<2)];
  }
  for (int k0 = 0; k0 < K; k0 += 32){
    __syncthreads();
    #pragma unroll
    for (int u=0;u<4;u++){
      int e = tid + u*256;
      int row = e>>3, kc = (e&7)<<2;
      At[(kc+0)*132 + row] = pa[u].x;
      At[(kc+1)*132 + row] = pa[u].y;
      At[(kc+2)*132 + row] = pa[u].z;
      At[(kc+3)*132 + row] = pa[u].w;
      *(float4*)&Ws[(e>>5)*HD + ((e&31)<<2)] = pw[u];
    }
    __syncthreads();
    if (k0 + 32 < K){
      #pragma unroll
      for (int u=0;u<4;u++){
        int e = tid + u*256;
        pa[u] = *(const float4*)&A[(size_t)(r0 + (e>>3))*K + (k0+32) + ((e&7)<<2)];
        pw[u] = *(const float4*)&W[(size_t)((k0+32) + (e>>5))*HD + ((e&31)<<2)];
      }
    }
    #pragma unroll
    for (int kk=0; kk<32; kk++){
      float4 a0 = *(const float4*)&At[kk*132 + tr*8];
      float4 a1 = *(const float4*)&At[kk*132 + tr*8 + 4];
      float4 w0 = *(const float4*)&Ws[kk*HD + c0];
      float4 w1 = *(const float4*)&Ws[kk*HD + c0 + 64];
      fma4(acc[0][0], a0.x, w0); fma4(acc[0][1], a0.x, w1);
      fma4(acc[1][0], a0.y, w0); fma4(acc[1][1], a0.y, w1);
      fma4(acc[2][0], a0.z, w0); fma4(acc[2][1], a0.z, w1);
      fma4(acc[3][0], a0.w, w0); fma4(acc[3][1], a0.w, w1);
      fma4(acc[4][0], a1.x, w0); fma4(acc[4][1], a1.x, w1);
      fma4(acc[5][0], a1.y, w0); fma4(acc[5][1], a1.y, w1);
      fma4(acc[6][0], a1.z, w0); fma4(acc[6][1], a1.z, w1);
      fma4(acc[7][0], a1.w, w0); fma4(acc[7][1], a1.w, w1);
    }
  }
  float4 b0 = *(const float4*)&bias[c0];
  float4 b1 = *(const float4*)&bias[c0+64];
  float4 s0 = make_float4(0,0,0,0), s1 = s0, q0 = s0, q1 = s0;
  if (STATS) __syncthreads();     // all LDS reads done before reuse as stats scratch
  #pragma unroll
  for (int j=0;j<8;j++){
    int row = r0 + tr*8 + j;
    float4 v0 = acc[j][0], v1 = acc[j][1];
    v0.x += b0.x; v0.y += b0.y; v0.z += b0.z; v0.w += b0.w;
    v1.x += b1.x; v1.y += b1.y; v1.z += b1.z; v1.w += b1.w;
    if (ACT == 1){
      v0.x = fmaxf(v0.x,0.f); v0.y = fmaxf(v0.y,0.f); v0.z = fmaxf(v0.z,0.f); v0.w = fmaxf(v0.w,0.f);
      v1.x = fmaxf(v1.x,0.f); v1.y = fmaxf(v1.y,0.f); v1.z = fmaxf(v1.z,0.f); v1.w = fmaxf(v1.w,0.f);
    }
    *(float4*)&C[(size_t)row*HD + c0] = v0;
    *(float4*)&C[(size_t)row*HD + c0 + 64] = v1;
    if (STATS){
      s0.x += v0.x; s0.y += v0.y; s0.z += v0.z; s0.w += v0.w;
      s1.x += v1.x; s1.y += v1.y; s1.z += v1.z; s1.w += v1.w;
      q0.x = fmaf(v0.x,v0.x,q0.x); q0.y = fmaf(v0.y,v0.y,q0.y);
      q0.z = fmaf(v0.z,v0.z,q0.z); q0.w = fmaf(v0.w,v0.w,q0.w);
      q1.x = fmaf(v1.x,v1.x,q1.x); q1.y = fmaf(v1.y,v1.y,q1.y);
      q1.z = fmaf(v1.z,v1.z,q1.z); q1.w = fmaf(v1.w,v1.w,q1.w);
    }
  }
  if (STATS){
    *(float4*)&At[tr*HD + c0]      = s0;
    *(float4*)&At[tr*HD + c0 + 64] = s1;
    *(float4*)&Ws[tr*HD + c0]      = q0;
    *(float4*)&Ws[tr*HD + c0 + 64] = q1;
    __syncthreads();
    if (tid < HD){
      float s = 0.f, q = 0.f;
      #pragma unroll
      for (int t=0;t<16;t++){ s += At[t*HD + tid]; q += Ws[t*HD + tid]; }
      part[blockIdx.x*HD + tid] = s;
      part[256*HD + blockIdx.x*HD + tid] = q;
    }
  }
}

// ---------------- BN finalize ----------------
__global__ __launch_bounds__(128) void k_bn_fin(const float* __restrict__ part, const float* __restrict__ gamma,
                                                const float* __restrict__ beta, float* __restrict__ scale,
                                                float* __restrict__ shift){
  int f = threadIdx.x;
  float s = 0.f, q = 0.f;
  for (int b=0;b<256;b++){ s += part[b*HD+f]; q += part[256*HD + b*HD + f]; }
  float mu  = s * (1.0f/NND);
  float var = q * (1.0f/NND) - mu*mu;
  float sc  = gamma[f] * rsqrtf(var + 1e-5f);
  scale[f] = sc;
  shift[f] = beta[f] - mu*sc;
}

// ---------------- fused: BN-apply (folded) + mean-aggregate + npool accumulate ----------------
// one block per node: max TLP for the random gather.
// z = sc*(raw_i + invdeg*sum_j raw_j) + sh*(1 + has_neighbors);  v_i = sc*raw_i+sh feeds npool.
__global__ __launch_bounds__(128) void k_agg_bn(const float* __restrict__ raw, const int* __restrict__ rowp,
                                                const int* __restrict__ csr, const float* __restrict__ invdeg,
                                                const float* __restrict__ scale, const float* __restrict__ shift,
                                                float* __restrict__ z, float* __restrict__ npool, int first){
  int i = blockIdx.x;
  int f = threadIdx.x;
  int a = rowp[i], bnd = rowp[i+1];
  float s = 0.f;
  for (int k = a; k < bnd; k++) s += raw[(size_t)csr[k]*HD + f];
  float sc = scale[f], sh = shift[f];
  size_t idx = (size_t)i*HD + f;
  float vi = fmaf(raw[idx], sc, sh);
  float zz = vi + fmaf(invdeg[i]*sc, s, (bnd > a) ? sh : 0.f);
  z[idx] = zz;
  npool[idx] = first ? vi : (npool[idx] + vi);
}

// final layer: npool += BN(raw) elementwise, vectorized
__global__ __launch_bounds__(256) void k_bn_acc(const float* __restrict__ raw, const float* __restrict__ scale,
                                                const float* __restrict__ shift, float* __restrict__ npool){
  int g = blockIdx.x*256 + threadIdx.x;     // over NND*32
  int c = (g & 31) << 2;
  size_t off = (size_t)g*4;
  float4 r = *(const float4*)&raw[off];
  float4 sc = *(const float4*)&scale[c];
  float4 sh = *(const float4*)&shift[c];
  float4 np = *(const float4*)&npool[off];
  np.x += fmaf(r.x, sc.x, sh.x);
  np.y += fmaf(r.y, sc.y, sh.y);
  np.z += fmaf(r.z, sc.z, sh.z);
  np.w += fmaf(r.w, sc.w, sh.w);
  *(float4*)&npool[off] = np;
}

// gsum[b] = sum over batch-b nodes of npool  (gpool = gsum/1024; counts are uniform so
// summing npool over layers == summing per-layer gpool)
__global__ __launch_bounds__(128) void k_gsum(const float* __restrict__ npool, float* __restrict__ gsum){
  int b = blockIdx.x >> 3, chunk = blockIdx.x & 7;
  int f = threadIdx.x;
  int r0 = (b << 10) + chunk*128;
  float s = 0.f;
  #pragma unroll 8
  for (int r=0;r<128;r++) s += npool[(size_t)(r0+r)*HD + f];
  atomicAdd(&gsum[b*HD + f], s);
}

// ---------------- policy path (selected 4096 node instances) ----------------
__global__ __launch_bounds__(256) void k_build_aug(const int* __restrict__ mrows, const int* __restrict__ mcols,
                                                   const float* __restrict__ npool, const float* __restrict__ gsum,
                                                   float* __restrict__ aug){
  int idx = blockIdx.x;     // 0..4095: first 2048 = row nodes, next 2048 = col nodes
  int t = threadIdx.x;
  int j = idx & 2047;
  int rg = mrows[j];
  int b = rg >> 10;
  int g = (idx >= 2048) ? ((b << 10) | mcols[j]) : rg;
  float v;
  if (t < 128) v = npool[(size_t)g*HD + t];
  else         v = gsum[b*HD + (t-128)] * (1.0f/1024.0f);
  aug[(size_t)idx*256 + t] = v;
}

// fused policy layer: C = tanh(A@W1+b1)@W2+b2.  64-row tile, T kept in LDS.
template<int K1>
__global__ __launch_bounds__(256) void k_pol(const float* __restrict__ A, const float* __restrict__ W1,
                                             const float* __restrict__ b1, const float* __restrict__ W2,
                                             const float* __restrict__ b2, float* __restrict__ C){
  __shared__ float S1[32*128 + 64*36];
  __shared__ float T[64*132];
  int tid = threadIdx.x;
  int r0 = blockIdx.x * 64;
  int tc = tid & 15, rg = tid >> 4;
  int c0 = tc * 4;
  float4 acc0[4], acc1[4];
  #pragma unroll
  for (int j=0;j<4;j++){ acc0[j] = make_float4(0,0,0,0); acc1[j] = make_float4(0,0,0,0); }
  for (int k0 = 0; k0 < K1; k0 += 32){
    __syncthreads();
    #pragma unroll
    for (int u=0;u<4;u++){
      int e = tid + u*256;
      *(float4*)&S1[(e>>5)*HD + ((e&31)<<2)] = *(const float4*)&W1[(size_t)(k0 + (e>>5))*HD + ((e&31)<<2)];
    }
    #pragma unroll
    for (int u=0;u<2;u++){
      int e = tid + u*256;
      *(float4*)&S1[4096 + (e>>3)*36 + ((e&7)<<2)] = *(const float4*)&A[(size_t)(r0 + (e>>3))*K1 + k0 + ((e&7)<<2)];
    }
    __syncthreads();
    #pragma unroll
    for (int kk=0; kk<32; kk+=4){
      float4 w0[4], w1[4];
      #pragma unroll
      for (int q=0;q<4;q++){
        w0[q] = *(const float4*)&S1[(kk+q)*HD + c0];
        w1[q] = *(const float4*)&S1[(kk+q)*HD + c0 + 64];
      }
      #pragma unroll
      for (int j=0;j<4;j++){
        float4 av = *(const float4*)&S1[4096 + (rg+16*j)*36 + kk];
        fma4(acc0[j], av.x, w0[0]); fma4(acc1[j], av.x, w1[0]);
        fma4(acc0[j], av.y, w0[1]); fma4(acc1[j], av.y, w1[1]);
        fma4(acc0[j], av.z, w0[2]); fma4(acc1[j], av.z, w1[2]);
        fma4(acc0[j], av.w, w0[3]); fma4(acc1[j], av.w, w1[3]);
      }
    }
  }
  {
    float4 bA = *(const float4*)&b1[c0];
    float4 bB = *(const float4*)&b1[c0+64];
    #pragma unroll
    for (int j=0;j<4;j++){
      int r = rg + 16*j;
      float4 v0 = acc0[j], v1 = acc1[j];
      v0.x = tanhf(v0.x + bA.x); v0.y = tanhf(v0.y + bA.y);
      v0.z = tanhf(v0.z + bA.z); v0.w = tanhf(v0.w + bA.w);
      v1.x = tanhf(v1.x + bB.x); v1.y = tanhf(v1.y + bB.y);
      v1.z = tanhf(v1.z + bB.z); v1.w = tanhf(v1.w + bB.w);
      *(float4*)&T[r*132 + c0] = v0;
      *(float4*)&T[r*132 + c0 + 64] = v1;
    }
  }
  float4 d0[4], d1[4];
  #pragma unroll
  for (int j=0;j<4;j++){ d0[j] = make_float4(0,0,0,0); d1[j] = make_float4(0,0,0,0); }
  for (int k0 = 0; k0 < HD; k0 += 32){
    __syncthreads();
    #pragma unroll
    for (int u=0;u<4;u++){
      int e = tid + u*256;
      *(float4*)&S1[(e>>5)*HD + ((e&31)<<2)] = *(const float4*)&W2[(size_t)(k0 + (e>>5))*HD + ((e&31)<<2)];
    }
    __syncthreads();
    #pragma unroll
    for (int kk=0; kk<32; kk+=4){
      float4 w0[4], w1[4];
      #pragma unroll
      for (int q=0;q<4;q++){
        w0[q] = *(const float4*)&S1[(kk+q)*HD + c0];
        w1[q] = *(const float4*)&S1[(kk+q)*HD + c0 + 64];
      }
      #pragma unroll
      for (int j=0;j<4;j++){
        float4 av = *(const float4*)&T[(rg+16*j)*132 + k0 + kk];
        fma4(d0[j], av.x, w0[0]); fma4(d1[j], av.x, w1[0]);
        fma4(d0[j], av.y, w0[1]); fma4(d1[j], av.y, w1[1]);
        fma4(d0[j], av.z, w0[2]); fma4(d1[j], av.z, w1[2]);
        fma4(d0[j], av.w, w0[3]); fma4(d1[j], av.w, w1[3]);
      }
    }
  }
  float4 bA = *(const float4*)&b2[c0];
  float4 bB = *(const float4*)&b2[c0+64];
  #pragma unroll
  for (int j=0;j<4;j++){
    int row = r0 + rg + 16*j;
    float4 v0 = d0[j], v1 = d1[j];
    v0.x += bA.x; v0.y += bA.y; v0.z += bA.z; v0.w += bA.w;
    v1.x += bB.x; v1.y += bB.y; v1.z += bB.z; v1.w += bB.w;
    *(float4*)&C[(size_t)row*HD + c0] = v0;
    *(float4*)&C[(size_t)row*HD + c0 + 64] = v1;
  }
}

// score + per-batch sparse softmax (dedup of repeated cells) + scatter
__global__ __launch_bounds__(64) void k_score(const float* __restrict__ Z, const int* __restrict__ mrows,
                                              const int* __restrict__ mcols, float* __restrict__ out){
  __shared__ int rr[64]; __shared__ int cc[64]; __shared__ float red[64];
  int b = blockIdx.x, f = threadIdx.x;
  int i = b*64 + f;
  int rg = mrows[i];
  int row = rg & 1023;
  int col = mcols[i];
  const float4* zr = (const float4*)&Z[(size_t)i*HD];
  const float4* zc = (const float4*)&Z[(size_t)(NPAIR + i)*HD];
  float s = 0.f;
  #pragma unroll
  for (int k=0;k<32;k++){
    float4 a = zr[k], c = zc[k];
    s = fmaf(a.x,c.x, fmaf(a.y,c.y, fmaf(a.z,c.z, fmaf(a.w,c.w, s))));
  }
  rr[f]=row; cc[f]=col; red[f]=s;
  __syncthreads();
  for (int d=32; d>0; d>>=1){
    if (f<d) red[f] = fmaxf(red[f], red[f+d]);
    __syncthreads();
  }
  float m = red[0];
  __syncthreads();
  bool first = true;
  for (int j=0;j<f;j++) if (rr[j]==row && cc[j]==col) first = false;
  float e = expf(s - m);
  red[f] = first ? e : 0.0f;
  __syncthreads();
  for (int d=32; d>0; d>>=1){
    if (f<d) red[f] += red[f+d];
    __syncthreads();
  }
  float denom = red[0];
  out[(size_t)b*1048576 + row*1024 + col] = e / denom;
}

extern "C" void kernel_launch(void* const* d_in, const int* in_sizes, int n_in,
                              void* d_out, int out_size, void* d_ws, size_t ws_size,
                              hipStream_t stream){
  const float* x     = (const float*)d_in[0];
  const int*   ei    = (const int*)d_in[1];
  const int*   mrows = (const int*)d_in[3];
  const int*   mcols = (const int*)d_in[4];
  const float* g0w1  = (const float*)d_in[5];
  const float* g0b1  = (const float*)d_in[6];
  const float* g0w2  = (const float*)d_in[7];
  const float* g0b2  = (const float*)d_in[8];
  const float* gw1   = (const float*)d_in[9];
  const float* gb1   = (const float*)d_in[10];
  const float* gw2   = (const float*)d_in[11];
  const float* gb2   = (const float*)d_in[12];
  const float* bng   = (const float*)d_in[13];
  const float* bnb   = (const float*)d_in[14];
  const float* p0w1  = (const float*)d_in[15];
  const float* p0b1  = (const float*)d_in[16];
  const float* p0w2  = (const float*)d_in[17];
  const float* p0b2  = (const float*)d_in[18];
  const float* pw1   = (const float*)d_in[19];
  const float* pb1   = (const float*)d_in[20];
  const float* pw2   = (const float*)d_in[21];
  const float* pb2   = (const float*)d_in[22];

  float* fw    = (float*)d_ws;
  float* bufRaw= fw;                        // N*H
  float* bufZ  = fw + 4194304;              // N*H
  float* bufA  = fw + 8388608;              // N*H
  float* npool = fw + 12582912;             // N*H
  float* z8    = fw + 16777216;             // N*8
  float* invdeg= fw + 17039360;             // N
  float* bnsc  = fw + 17072128;             // H
  float* bnsh  = fw + 17072256;             // H
  float* part  = fw + 17072384;             // 2*256*H
  int*   cnt   = (int*)(fw + 17137920);     // N
  int*   fillc = cnt + NND;                 // N
  float* gsum  = (float*)(fillc + NND);     // B*H
  int*   rowp  = (int*)(gsum + 4096);       // N+1
  int*   csr   = rowp + NND + 1;            // E
  float* aug   = bufA;                      // 4096*256 (after GIN)
  float* pX    = bufZ;                      // 4096*128
  float* pY    = bufZ + 524288;             // 4096*128
  float* pZ    = bufRaw;                    // 4096*128

  const int* src = ei;
  const int* dst = ei + NE;

  hipLaunchKernelGGL(k_zero, dim3(2048), dim3(256), 0, stream, (float4*)d_out, out_size/4);
  hipMemsetAsync(cnt, 0, (size_t)(NND + NND + 4096)*4, stream);   // cnt, fillc, gsum

  hipLaunchKernelGGL(k_count, dim3(NE/256), dim3(256), 0, stream, dst, cnt);
  hipLaunchKernelGGL(k_scan, dim3(1), dim3(1024), 0, stream, cnt, rowp, invdeg);
  hipLaunchKernelGGL(k_fill, dim3(NE/256), dim3(256), 0, stream, src, dst, rowp, fillc, csr);

  // layer 0
  hipLaunchKernelGGL(k_agg8, dim3(NND/256), dim3(256), 0, stream, x, rowp, csr, invdeg, z8);
  hipLaunchKernelGGL(k_gemm8, dim3(NND*HD/256), dim3(256), 0, stream, z8, g0w1, g0b1, bufA);
  hipLaunchKernelGGL((k_gemm128<1,1>), dim3(NND/128), dim3(256), 0, stream, bufA, g0w2, g0b2, bufRaw, part);
  hipLaunchKernelGGL(k_bn_fin, dim3(1), dim3(128), 0, stream, part, bng, bnb, bnsc, bnsh);

  // layers 1..3 (agg of layer l consumes raw of layer l-1 and accumulates npool)
  for (int l=0;l<3;l++){
    hipLaunchKernelGGL(k_agg_bn, dim3(NND), dim3(128), 0, stream, bufRaw, rowp, csr, invdeg,
                       bnsc, bnsh, bufZ, npool, (l==0) ? 1 : 0);
    hipLaunchKernelGGL((k_gemm128<1,0>), dim3(NND/128), dim3(256), 0, stream, bufZ, gw1 + l*16384, gb1 + l*128, bufA, part);
    hipLaunchKernelGGL((k_gemm128<1,1>), dim3(NND/128), dim3(256), 0, stream, bufA, gw2 + l*16384, gb2 + l*128, bufRaw, part);
    hipLaunchKernelGGL(k_bn_fin, dim3(1), dim3(128), 0, stream, part, bng + (l+1)*128, bnb + (l+1)*128, bnsc, bnsh);
  }
  // layer 3's npool contribution, then gpool from npool
  hipLaunchKernelGGL(k_bn_acc, dim3(NND*32/256), dim3(256), 0, stream, bufRaw, bnsc, bnsh, npool);
  hipLaunchKernelGGL(k_gsum, dim3(256), dim3(128), 0, stream, npool, gsum);

  // policy on the 4096 referenced node instances only
  hipLaunchKernelGGL(k_build_aug, dim3(4096), dim3(256), 0, stream, mrows, mcols, npool, gsum, aug);
  hipLaunchKernelGGL((k_pol<256>), dim3(64), dim3(256), 0, stream, aug, p0w1, p0b1, p0w2, p0b2, pX);
  hipLaunchKernelGGL((k_pol<128>), dim3(64), dim3(256), 0, stream, pX, pw1, pb1, pw2, pb2, pY);
  hipLaunchKernelGGL((k_pol<128>), dim3(64), dim3(256), 0, stream, pY, pw1 + 16384, pb1 + 128, pw2 + 16384, pb2 + 128, pZ);

  hipLaunchKernelGGL(k_score, dim3(32), dim3(64), 0, stream, pZ, mrows, mcols, (float*)d_out);
}